// Round 1
// baseline (260.056 us; speedup 1.0000x reference)
//
#include <hip/hip_runtime.h>
#include <hip/hip_bf16.h>

#define N_TOT 16384
#define B_HALF 8192
#define D 256
#define BN 64
#define NSPLIT 8
#define COLS_PER_SPLIT (N_TOT / NSPLIT)   // 2048
#define NTILES (COLS_PER_SPLIT / BN)      // 32
#define BM 128                            // rows per block = 4 waves * 32

typedef short bf16x8 __attribute__((ext_vector_type(8)));
typedef float f32x4 __attribute__((ext_vector_type(4)));

__device__ __forceinline__ ushort f2bf(float x) {
    uint32_t u = __float_as_uint(x);
    uint32_t r = u + 0x7FFFu + ((u >> 16) & 1u);   // RNE; inputs are finite normals
    return (ushort)(r >> 16);
}

// ---------------- stage 1: fp32 -> bf16 concat ----------------
__global__ void convert_kernel(const float* __restrict__ z1,
                               const float* __restrict__ z2,
                               ushort* __restrict__ zb) {
    int idx = blockIdx.x * blockDim.x + threadIdx.x;   // over N_TOT*D/4
    const int total4 = N_TOT * D / 4;
    if (idx >= total4) return;
    int i = idx * 4;
    const int half_elems = B_HALF * D;
    const float* s = (i < half_elems) ? (z1 + i) : (z2 + (i - half_elems));
    float4 f = *reinterpret_cast<const float4*>(s);
    ushort4 o;
    o.x = f2bf(f.x); o.y = f2bf(f.y); o.z = f2bf(f.z); o.w = f2bf(f.w);
    *reinterpret_cast<ushort4*>(zb + i) = o;
}

// ---------------- stage 2: flash-style LSE sweep ----------------
__global__ __launch_bounds__(256)
void infonce_main(const ushort* __restrict__ zb,
                  const float* __restrict__ lsp,
                  float* __restrict__ part) {
    __shared__ ushort ks[BN * D];   // 32 KB, XOR-swizzled

    const int tid  = threadIdx.x;
    const int wid  = tid >> 6;
    const int lane = tid & 63;
    const int g    = lane >> 4;     // 0..3
    const int lg   = lane & 15;     // 0..15
    const int qrow0   = blockIdx.x * BM + wid * 32;
    const int split   = blockIdx.y;
    const int colbase = split * COLS_PER_SPLIT;

    const float scale = fminf(__expf(lsp[0]), 100.0f);

    // A fragments: 2 M-frags x 8 K-frags, resident all sweep
    bf16x8 afrag[2][8];
#pragma unroll
    for (int mi = 0; mi < 2; ++mi) {
        int r = qrow0 + mi * 16 + lg;
#pragma unroll
        for (int kk = 0; kk < 8; ++kk)
            afrag[mi][kk] = *reinterpret_cast<const bf16x8*>(zb + r * D + kk * 32 + g * 8);
    }

    // per-lane online-LSE state for 8 row-slots (rows qrow0 + mi*16 + g*4 + j)
    float m_run[8], l_run[8], t_acc[8];
#pragma unroll
    for (int s = 0; s < 8; ++s) { m_run[s] = -1e30f; l_run[s] = 0.0f; t_acc[s] = 0.0f; }

    for (int t = 0; t < NTILES; ++t) {
        const int crow0 = colbase + t * BN;

        // reg-stage the K tile (coalesced 16B loads)
        bf16x8 stg[8];
#pragma unroll
        for (int it = 0; it < 8; ++it) {
            int ci = it * 256 + tid;        // 2048 chunks of 8 bf16
            int rr = ci >> 5;
            int c8 = ci & 31;
            stg[it] = *reinterpret_cast<const bf16x8*>(zb + (crow0 + rr) * D + c8 * 8);
        }
        __syncthreads();                     // prior tile fully consumed
#pragma unroll
        for (int it = 0; it < 8; ++it) {
            int ci  = it * 256 + tid;
            int rr  = ci >> 5;
            int c8  = ci & 31;
            int col = (c8 * 8) ^ ((rr & 7) * 8);   // XOR swizzle, 16B granules
            *reinterpret_cast<bf16x8*>(ks + rr * D + col) = stg[it];
        }
        __syncthreads();

        f32x4 acc[2][4];
#pragma unroll
        for (int mi = 0; mi < 2; ++mi)
#pragma unroll
            for (int n = 0; n < 4; ++n) acc[mi][n] = (f32x4){0.f, 0.f, 0.f, 0.f};

#pragma unroll
        for (int kk = 0; kk < 8; ++kk) {
            bf16x8 b[4];
#pragma unroll
            for (int n = 0; n < 4; ++n) {
                int rr  = n * 16 + lg;
                int col = (kk * 32 + g * 8) ^ ((rr & 7) * 8);
                b[n] = *reinterpret_cast<const bf16x8*>(ks + rr * D + col);
            }
#pragma unroll
            for (int mi = 0; mi < 2; ++mi)
#pragma unroll
                for (int n = 0; n < 4; ++n)
                    acc[mi][n] = __builtin_amdgcn_mfma_f32_16x16x32_bf16(
                        afrag[mi][kk], b[n], acc[mi][n], 0, 0, 0);
        }

        // epilogue: scale, target capture, diag mask, per-lane online LSE
#pragma unroll
        for (int mi = 0; mi < 2; ++mi) {
#pragma unroll
            for (int j = 0; j < 4; ++j) {
                const int slot = mi * 4 + j;
                const int r    = qrow0 + mi * 16 + g * 4 + j;
                const int tcol = (r < B_HALF) ? r + B_HALF : r - B_HALF;
                float v[4];
                float vmax = -1e30f;
#pragma unroll
                for (int n = 0; n < 4; ++n) {
                    int c   = crow0 + n * 16 + lg;
                    float x = acc[mi][n][j] * scale;
                    if (c == tcol) t_acc[slot] += x;
                    if (c == r)    x = -1e30f;
                    v[n] = x;
                    vmax = fmaxf(vmax, x);
                }
                float m_old = m_run[slot];
                float m_new = fmaxf(m_old, vmax);
                float lr = l_run[slot] * __expf(m_old - m_new);
#pragma unroll
                for (int n = 0; n < 4; ++n) lr += __expf(v[n] - m_new);
                m_run[slot] = m_new;
                l_run[slot] = lr;
            }
        }
    }

    // merge (m,l,t) across the 16-lane column group
#pragma unroll
    for (int s = 0; s < 8; ++s) {
        float m = m_run[s], l = l_run[s], tv = t_acc[s];
#pragma unroll
        for (int off = 1; off < 16; off <<= 1) {
            float mo = __shfl_xor(m, off);
            float lo = __shfl_xor(l, off);
            float to = __shfl_xor(tv, off);
            float mm = fmaxf(m, mo);
            l = l * __expf(m - mm) + lo * __expf(mo - mm);
            m = mm;
            tv += to;
        }
        m_run[s] = m; l_run[s] = l; t_acc[s] = tv;
    }
    if (lg == 0) {
#pragma unroll
        for (int mi = 0; mi < 2; ++mi)
#pragma unroll
            for (int j = 0; j < 4; ++j) {
                int r = qrow0 + mi * 16 + g * 4 + j;
                int s = mi * 4 + j;
                float* p = part + (size_t)(r * NSPLIT + split) * 3;
                p[0] = m_run[s]; p[1] = l_run[s]; p[2] = t_acc[s];
            }
    }
}

// ---------------- stage 3: per-row combine + deterministic sum ----------------
__global__ void reduce_kernel(const float* __restrict__ part,
                              float* __restrict__ bsum) {
    int r = blockIdx.x * 256 + threadIdx.x;
    float m = -1e30f, l = 0.f, tv = 0.f;
#pragma unroll
    for (int s = 0; s < NSPLIT; ++s) {
        const float* p = part + (size_t)(r * NSPLIT + s) * 3;
        float ms = p[0], lv = p[1], ts = p[2];
        float mm = fmaxf(m, ms);
        l = l * __expf(m - mm) + lv * __expf(ms - mm);
        m = mm;
        tv += ts;
    }
    float v = m + __logf(l) - tv;   // nll for this row
#pragma unroll
    for (int off = 1; off < 64; off <<= 1) v += __shfl_xor(v, off);
    __shared__ float ws4[4];
    int lane = threadIdx.x & 63, wid = threadIdx.x >> 6;
    if (lane == 0) ws4[wid] = v;
    __syncthreads();
    if (threadIdx.x == 0)
        bsum[blockIdx.x] = ws4[0] + ws4[1] + ws4[2] + ws4[3];
}

__global__ void final_kernel(const float* __restrict__ bsum,
                             float* __restrict__ out) {
    float v = bsum[threadIdx.x];   // 64 threads, 64 block sums
#pragma unroll
    for (int off = 1; off < 64; off <<= 1) v += __shfl_xor(v, off);
    if (threadIdx.x == 0) out[0] = v * (1.0f / (float)N_TOT);
}

extern "C" void kernel_launch(void* const* d_in, const int* in_sizes, int n_in,
                              void* d_out, int out_size, void* d_ws, size_t ws_size,
                              hipStream_t stream) {
    const float* z1 = (const float*)d_in[0];
    const float* z2 = (const float*)d_in[1];
    const float* ls = (const float*)d_in[2];
    float* out = (float*)d_out;

    ushort* zb   = (ushort*)d_ws;                                   // 8 MB
    float*  part = (float*)((char*)d_ws + (size_t)N_TOT * D * 2);   // 1.5 MB
    float*  bsum = (float*)((char*)part + (size_t)N_TOT * NSPLIT * 3 * sizeof(float));

    convert_kernel<<<(N_TOT * D / 4 + 255) / 256, 256, 0, stream>>>(z1, z2, zb);
    dim3 grid(N_TOT / BM, NSPLIT);
    infonce_main<<<grid, 256, 0, stream>>>(zb, ls, part);
    reduce_kernel<<<N_TOT / 256, 256, 0, stream>>>(part, bsum);
    final_kernel<<<1, 64, 0, stream>>>(bsum, out);
}

// Round 2
// 155.831 us; speedup vs baseline: 1.6688x; 1.6688x over previous
//
#include <hip/hip_runtime.h>
#include <hip/hip_bf16.h>

#define N_TOT 16384
#define B_HALF 8192
#define D 256
#define BN 64
#define NSPLIT 8
#define COLS_PER_SPLIT (N_TOT / NSPLIT)   // 2048
#define NTILES (COLS_PER_SPLIT / BN)      // 32
#define BM 128                            // rows per block = 4 waves * 32

#define LOG2E 1.4426950408889634f
#define LN2   0.6931471805599453f

typedef short bf16x8 __attribute__((ext_vector_type(8)));
typedef float f32x4 __attribute__((ext_vector_type(4)));

__device__ __forceinline__ float fexp2(float x) {
#if __has_builtin(__builtin_amdgcn_exp2f)
    return __builtin_amdgcn_exp2f(x);
#else
    return __expf(x * LN2);
#endif
}

__device__ __forceinline__ ushort f2bf(float x) {
    uint32_t u = __float_as_uint(x);
    uint32_t r = u + 0x7FFFu + ((u >> 16) & 1u);   // RNE; inputs finite
    return (ushort)(r >> 16);
}

// ---------------- stage 1: fp32 -> prescaled bf16 concat ----------------
// zbs = z * sqrt(scale * log2e)  so that  zbs_i . zbs_j = log2-domain logit
__global__ void convert_kernel(const float* __restrict__ z1,
                               const float* __restrict__ z2,
                               const float* __restrict__ lsp,
                               ushort* __restrict__ zb) {
    const float scale = fminf(__expf(lsp[0]), 100.0f);
    const float s = __fsqrt_rn(scale * LOG2E);
    int idx = blockIdx.x * blockDim.x + threadIdx.x;   // over N_TOT*D/4
    const int total4 = N_TOT * D / 4;
    if (idx >= total4) return;
    int i = idx * 4;
    const int half_elems = B_HALF * D;
    const float* src = (i < half_elems) ? (z1 + i) : (z2 + (i - half_elems));
    float4 f = *reinterpret_cast<const float4*>(src);
    ushort4 o;
    o.x = f2bf(f.x * s); o.y = f2bf(f.y * s); o.z = f2bf(f.z * s); o.w = f2bf(f.w * s);
    *reinterpret_cast<ushort4*>(zb + i) = o;
}

// ---------------- stage 1b: exact fp32 target logits ----------------
// tnat[r] = scale * dot(z[r], z[r^B_HALF])   (natural domain, exact fp32)
__global__ void target_kernel(const float* __restrict__ z1,
                              const float* __restrict__ z2,
                              const float* __restrict__ lsp,
                              float* __restrict__ tnat) {
    const int r    = blockIdx.x * 4 + (threadIdx.x >> 6);
    const int lane = threadIdx.x & 63;
    const float* zr = (r < B_HALF) ? (z1 + (size_t)r * D) : (z2 + (size_t)(r - B_HALF) * D);
    const float* zp = (r < B_HALF) ? (z2 + (size_t)r * D) : (z1 + (size_t)(r - B_HALF) * D);
    float4 a = *reinterpret_cast<const float4*>(zr + lane * 4);
    float4 b = *reinterpret_cast<const float4*>(zp + lane * 4);
    float d = a.x * b.x + a.y * b.y + a.z * b.z + a.w * b.w;
#pragma unroll
    for (int off = 1; off < 64; off <<= 1) d += __shfl_xor(d, off);
    if (lane == 0) {
        const float scale = fminf(__expf(lsp[0]), 100.0f);
        tnat[r] = scale * d;
    }
}

// ---------------- epilogue helper ----------------
template<bool MASKD>
__device__ __forceinline__ void epilogue(const f32x4 (&acc)[2][4],
                                         float (&m2)[8], float (&l2)[8],
                                         int qrow0, int crow0, int g, int lg) {
#pragma unroll
    for (int mi = 0; mi < 2; ++mi) {
#pragma unroll
        for (int j = 0; j < 4; ++j) {
            const int slot = mi * 4 + j;
            float v[4];
#pragma unroll
            for (int n = 0; n < 4; ++n) {
                float x = acc[mi][n][j];
                if (MASKD) {
                    const int r = qrow0 + mi * 16 + g * 4 + j;
                    const int c = crow0 + n * 16 + lg;
                    if (c == r) x = -1e30f;
                }
                v[n] = x;
            }
            float m_old = m2[slot];
            float m_new = fmaxf(fmaxf(fmaxf(v[0], v[1]), fmaxf(v[2], v[3])), m_old);
            float lr = l2[slot] * fexp2(m_old - m_new);
            lr += fexp2(v[0] - m_new);
            lr += fexp2(v[1] - m_new);
            lr += fexp2(v[2] - m_new);
            lr += fexp2(v[3] - m_new);
            m2[slot] = m_new;
            l2[slot] = lr;
        }
    }
}

// ---------------- stage 2: flash-style LSE sweep ----------------
__global__ __launch_bounds__(256)
void infonce_main(const ushort* __restrict__ zbs,
                  float* __restrict__ part) {
    __shared__ ushort ks[BN * D];   // 32 KB, LINEAR layout (content pre-swizzled at source)

    const int tid  = threadIdx.x;
    const int wid  = tid >> 6;
    const int lane = tid & 63;
    const int g    = lane >> 4;     // 0..3
    const int lg   = lane & 15;     // 0..15
    const int swr  = lg & 7;        // read-side XOR key
    const int qrow0   = blockIdx.x * BM + wid * 32;
    const int split   = blockIdx.y;
    const int colbase = split * COLS_PER_SPLIT;

    // A fragments: rows qrow0+mi*16+lg, k = kk*32 + g*8 + [0..7]
    bf16x8 afrag[2][8];
#pragma unroll
    for (int mi = 0; mi < 2; ++mi) {
        const ushort* ap = zbs + (size_t)(qrow0 + mi * 16 + lg) * D + g * 8;
#pragma unroll
        for (int kk = 0; kk < 8; ++kk)
            afrag[mi][kk] = *reinterpret_cast<const bf16x8*>(ap + kk * 32);
    }

    float m2[8], l2[8];
#pragma unroll
    for (int s = 0; s < 8; ++s) { m2[s] = -1e30f; l2[s] = 0.0f; }

    // staging thread-constants: slot = it*256 + tid ; rr = slot>>5 ; c8 = slot&31
    // rr = it*8 + (tid>>5)  ->  rr&7 == (tid>>5) is it-invariant
    const int rrb  = tid >> 5;                 // 0..7
    const int gsrc = (tid & 31) ^ rrb;         // pre-swizzled source granule
    const ushort* src0 = zbs + (size_t)rrb * D + gsrc * 8;

    for (int t = 0; t < NTILES; ++t) {
        const int crow0 = colbase + t * BN;
        const ushort* srcT = src0 + (size_t)crow0 * D;

        __syncthreads();   // all waves done reading previous tile
#pragma unroll
        for (int it = 0; it < 8; ++it) {
            __builtin_amdgcn_global_load_lds(
                (const __attribute__((address_space(1))) void*)(srcT + it * 8 * D),
                (__attribute__((address_space(3))) void*)&ks[it * 2048 + wid * 512],
                16, 0, 0);
        }
        __syncthreads();   // drains vmcnt -> tile resident

        f32x4 acc[2][4];
#pragma unroll
        for (int mi = 0; mi < 2; ++mi)
#pragma unroll
            for (int n = 0; n < 4; ++n) acc[mi][n] = (f32x4){0.f, 0.f, 0.f, 0.f};

#pragma unroll
        for (int kk = 0; kk < 8; ++kk) {
            bf16x8 b[4];
#pragma unroll
            for (int n = 0; n < 4; ++n) {
                const int rr   = n * 16 + lg;
                const int gran = (kk * 4 + g) ^ swr;
                b[n] = *reinterpret_cast<const bf16x8*>(ks + rr * D + gran * 8);
            }
#pragma unroll
            for (int mi = 0; mi < 2; ++mi)
#pragma unroll
                for (int n = 0; n < 4; ++n)
                    acc[mi][n] = __builtin_amdgcn_mfma_f32_16x16x32_bf16(
                        afrag[mi][kk], b[n], acc[mi][n], 0, 0, 0);
        }

        // diagonal can touch this tile only when the 64-col block matches (wave-uniform)
        if ((qrow0 >> 6) == (crow0 >> 6))
            epilogue<true >(acc, m2, l2, qrow0, crow0, g, lg);
        else
            epilogue<false>(acc, m2, l2, qrow0, crow0, g, lg);
    }

    // merge (m,l) across the 16-lane column group
#pragma unroll
    for (int s = 0; s < 8; ++s) {
        float m = m2[s], l = l2[s];
#pragma unroll
        for (int off = 1; off < 16; off <<= 1) {
            float mo = __shfl_xor(m, off);
            float lo = __shfl_xor(l, off);
            float mm = fmaxf(m, mo);
            l = l * fexp2(m - mm) + lo * fexp2(mo - mm);
            m = mm;
        }
        m2[s] = m; l2[s] = l;
    }
    if (lg == 0) {
#pragma unroll
        for (int mi = 0; mi < 2; ++mi)
#pragma unroll
            for (int j = 0; j < 4; ++j) {
                int r = qrow0 + mi * 16 + g * 4 + j;
                int s = mi * 4 + j;
                float* p = part + (size_t)(r * NSPLIT + split) * 2;
                p[0] = m2[s]; p[1] = l2[s];
            }
    }
}

// ---------------- stage 3: per-row combine + deterministic sum ----------------
__global__ void reduce_kernel(const float* __restrict__ part,
                              const float* __restrict__ tnat,
                              float* __restrict__ bsum) {
    int r = blockIdx.x * 256 + threadIdx.x;
    float m = -1e30f, l = 0.f;
#pragma unroll
    for (int s = 0; s < NSPLIT; ++s) {
        const float* p = part + (size_t)(r * NSPLIT + s) * 2;
        float ms = p[0], lv = p[1];
        float mm = fmaxf(m, ms);
        l = l * fexp2(m - mm) + lv * fexp2(ms - mm);
        m = mm;
    }
    float v = LN2 * (m + __log2f(l)) - tnat[r];   // nll for this row
#pragma unroll
    for (int off = 1; off < 64; off <<= 1) v += __shfl_xor(v, off);
    __shared__ float ws4[4];
    int lane = threadIdx.x & 63, wid = threadIdx.x >> 6;
    if (lane == 0) ws4[wid] = v;
    __syncthreads();
    if (threadIdx.x == 0)
        bsum[blockIdx.x] = ws4[0] + ws4[1] + ws4[2] + ws4[3];
}

__global__ void final_kernel(const float* __restrict__ bsum,
                             float* __restrict__ out) {
    float v = bsum[threadIdx.x];   // 64 threads, 64 block sums
#pragma unroll
    for (int off = 1; off < 64; off <<= 1) v += __shfl_xor(v, off);
    if (threadIdx.x == 0) out[0] = v * (1.0f / (float)N_TOT);
}

extern "C" void kernel_launch(void* const* d_in, const int* in_sizes, int n_in,
                              void* d_out, int out_size, void* d_ws, size_t ws_size,
                              hipStream_t stream) {
    const float* z1 = (const float*)d_in[0];
    const float* z2 = (const float*)d_in[1];
    const float* ls = (const float*)d_in[2];
    float* out = (float*)d_out;

    ushort* zbs  = (ushort*)d_ws;                                        // 8 MB
    float*  part = (float*)((char*)d_ws + (size_t)N_TOT * D * 2);        // 1 MB
    float*  tnat = (float*)((char*)part + (size_t)N_TOT * NSPLIT * 2 * sizeof(float));
    float*  bsum = (float*)((char*)tnat + (size_t)N_TOT * sizeof(float));

    convert_kernel<<<(N_TOT * D / 4 + 255) / 256, 256, 0, stream>>>(z1, z2, ls, zbs);
    target_kernel<<<N_TOT / 4, 256, 0, stream>>>(z1, z2, ls, tnat);
    dim3 grid(N_TOT / BM, NSPLIT);
    infonce_main<<<grid, 256, 0, stream>>>(zbs, part);
    reduce_kernel<<<N_TOT / 256, 256, 0, stream>>>(part, tnat, bsum);
    final_kernel<<<1, 64, 0, stream>>>(bsum, out);
}